// Round 11
// baseline (1174.788 us; speedup 1.0000x reference)
//
#include <hip/hip_runtime.h>
#include <math.h>

#define T_DIM 512
#define B_DIM 256
#define D_DIM 256
#define H_DIM 256
#define G_DIM 1024   // 4*H
#define K_DIM 512    // D + H
#define NROUNDS 40
#define CHAIN_K 12   // rounds 0..11 batched; steps >=12 via per-segment finisher

typedef __attribute__((ext_vector_type(8))) short short8;
typedef __attribute__((ext_vector_type(4))) float f32x4;

__device__ __forceinline__ unsigned int f2bf(float f) {
    unsigned int b = __float_as_uint(f);
    return (b + 0x7FFFu + ((b >> 16) & 1u)) >> 16;   // round-to-nearest-even bf16
}
__device__ __forceinline__ unsigned long long pack4(float4 v) {
    const unsigned int lo = (f2bf(v.y) << 16) | f2bf(v.x);
    const unsigned int hi = (f2bf(v.w) << 16) | f2bf(v.z);
    return ((unsigned long long)hi << 32) | lo;
}
__device__ __forceinline__ float sigm(float x) { return 1.0f / (1.0f + __expf(-x)); }
__device__ __forceinline__ float tanh_fast(float x) { return 2.0f / (1.0f + __expf(-2.0f * x)) - 1.0f; }

// async 16B/lane global->LDS (dest = wave-uniform base + lane*16; SOURCE is per-lane)
__device__ __forceinline__ void dma16(const void* g, void* l) {
    __builtin_amdgcn_global_load_lds(
        (const __attribute__((address_space(1))) void*)g,
        (__attribute__((address_space(3))) void*)l, 16, 0, 0);
}

// Prepack W into MFMA B-fragment order, bf16.
// short idx ((nt*16+ks)*64+l)*8+j  <->  g = nt*16+(l&15), k = ks*32+((l>>4)<<3)+j
__global__ __launch_bounds__(256) void k_prep_weights(
    const float* __restrict__ W_ih, const float* __restrict__ W_hh,
    const float* __restrict__ b_ih, const float* __restrict__ b_hh,
    unsigned int* __restrict__ Wb, float* __restrict__ bias)
{
    const int idx = blockIdx.x * 256 + threadIdx.x;   // 0 .. 262143
    const int jp = idx & 3, l = (idx >> 2) & 63, ks = (idx >> 8) & 15, nt = idx >> 12;
    const int g = nt * 16 + (l & 15);
    const int k0 = ks * 32 + ((l >> 4) << 3) + 2 * jp;
    const float w0 = (k0 < D_DIM) ? W_ih[g * D_DIM + k0] : W_hh[g * H_DIM + (k0 - D_DIM)];
    const float w1 = (k0 + 1 < D_DIM) ? W_ih[g * D_DIM + k0 + 1] : W_hh[g * H_DIM + (k0 + 1 - D_DIM)];
    Wb[idx] = (f2bf(w1) << 16) | f2bf(w0);
    if (idx < G_DIM) bias[idx] = b_ih[idx] + b_hh[idx];
}

// Prepack W k-major for the finisher GEMV.
__global__ __launch_bounds__(256) void k_prep_wq(
    const float* __restrict__ W_ih, const float* __restrict__ W_hh,
    unsigned long long* __restrict__ Wq)
{
    const int idx = blockIdx.x * 256 + threadIdx.x;   // 0..131071
    const int kq = idx >> 10, g = idx & (G_DIM - 1);
    float w[4];
    #pragma unroll
    for (int j = 0; j < 4; ++j) {
        const int k = kq * 4 + j;
        w[j] = (k < D_DIM) ? W_ih[g * D_DIM + k] : W_hh[g * H_DIM + (k - D_DIM)];
    }
    Wq[idx] = pack4((float4){w[0], w[1], w[2], w[3]});
}

// ab x-half: ab[pos*512 + k] = bf16(x[pos][k]), k 0..255 (linear order).
__global__ __launch_bounds__(256) void k_prep_ab(
    const float* __restrict__ x, unsigned long long* __restrict__ ab_u64)
{
    const int idx = blockIdx.x * 256 + threadIdx.x;      // (pos, 16B chunk): TB*64
    const int pos = idx >> 6, ch = idx & 63;             // ch < 32 -> x half only
    if (ch >= 32) return;
    const float4 v0 = *(const float4*)(x + (size_t)pos * D_DIM + ch * 8);
    const float4 v1 = *(const float4*)(x + (size_t)pos * D_DIM + ch * 8 + 4);
    ab_u64[(size_t)pos * 128 + ch * 2]     = pack4(v0);
    ab_u64[(size_t)pos * 128 + ch * 2 + 1] = pack4(v1);
}

// ab h-half prefill for reset rows (done==1 -> 0) and t==0 (!done -> h0).
__global__ __launch_bounds__(256) void k_prefill(
    const float* __restrict__ h0, const int* __restrict__ done,
    unsigned long long* __restrict__ ab_u64)
{
    const int idx = blockIdx.x * 256 + threadIdx.x;      // (pos, chunk32): TB*32
    const int pos = idx >> 5, ch = idx & 31;
    const int d = done[pos];
    if (!d && pos >= B_DIM) return;                      // not a reset row
    unsigned long long v0 = 0ull, v1 = 0ull;
    if (!d) {                                            // t==0, use h0
        const float4 a = *(const float4*)(h0 + (size_t)(pos & (B_DIM - 1)) * H_DIM + ch * 8);
        const float4 b = *(const float4*)(h0 + (size_t)(pos & (B_DIM - 1)) * H_DIM + ch * 8 + 4);
        v0 = pack4(a); v1 = pack4(b);
    }
    ab_u64[(size_t)pos * 128 + 64 + ch * 2]     = v0;
    ab_u64[(size_t)pos * 128 + 64 + ch * 2 + 1] = v1;
}

// Parallel kmap + histogram (kmap = true steps since reset; bins clamp).
__global__ __launch_bounds__(256) void k_kmap(
    const int* __restrict__ done, int* __restrict__ kmap, int* __restrict__ counts)
{
    __shared__ int lcnt[NROUNDS];
    const int tid = threadIdx.x;
    if (tid < NROUNDS) lcnt[tid] = 0;
    __syncthreads();
    const int t = blockIdx.x, b = tid;
    int kv = t;
    for (int tt = t; tt >= 0; --tt) {
        if (done[tt * B_DIM + b]) { kv = t - tt; break; }
    }
    kmap[t * B_DIM + b] = kv;
    const int bin = kv < NROUNDS ? kv : NROUNDS - 1;
    atomicAdd(&lcnt[bin], 1);
    __syncthreads();
    if (tid < NROUNDS && lcnt[tid] > 0) atomicAdd(&counts[tid], lcnt[tid]);
}

__global__ __launch_bounds__(64) void k_offs(
    const int* __restrict__ counts, int* __restrict__ offs, int* __restrict__ cursor)
{
    if (threadIdx.x == 0) {
        int s = 0;
        for (int i = 0; i < NROUNDS; ++i) { offs[i] = s; s += counts[i]; }
    }
    if (threadIdx.x < NROUNDS) cursor[threadIdx.x] = 0;
}

__global__ __launch_bounds__(256) void k_scatter(
    const int* __restrict__ kmap, const int* __restrict__ offs,
    int* __restrict__ cursor, int* __restrict__ rowlist)
{
    __shared__ int lcnt[NROUNDS];
    __shared__ int gbase[NROUNDS];
    const int tid = threadIdx.x;
    if (tid < NROUNDS) lcnt[tid] = 0;
    __syncthreads();
    const int pos = blockIdx.x * 256 + tid;
    const int kv0 = kmap[pos];
    const int kv = kv0 < NROUNDS ? kv0 : NROUNDS - 1;
    const int lrank = atomicAdd(&lcnt[kv], 1);
    __syncthreads();
    if (tid < NROUNDS && lcnt[tid] > 0) gbase[tid] = atomicAdd(&cursor[tid], lcnt[tid]);
    __syncthreads();
    rowlist[offs[kv] + gbase[kv] + lrank] = pos;
}

// ================== R=128 x C=512 pipelined round ==================
// tile = (rt, cb): 128 rows x 512 cols (cols gate-strided: nt = gt*16 + cb*8 + w).
// Block 512 thr (8 waves). Wave w: 4 nt (units [cb*128+w*16, +16) x 4 gates) x all 128 rows.
// A: ab rows streamed in 4-ks chunks [128 rows][256B], XOR source-swizzled
//    (phys slot s holds logical s ^ (row&15)), double-buffered (2x32KB).
// B: wave-private dbuf frags B_lds[w][par][4nt][1KB] (2x32KB).
// Counted vmcnt: (g<3 && ksl<=1) -> 8 else 4. Barriers: ksl0 (A-chunk cross-wave
// ready) + group-end (A-buf overwrite guard) = 8/tile.
__global__ __launch_bounds__(512, 2) void k_round(
    const short* __restrict__ ab, const float* __restrict__ c0,
    const int* __restrict__ done,
    const short* __restrict__ Wb, const float* __restrict__ bias,
    const int* __restrict__ counts, const int* __restrict__ offs,
    const int* __restrict__ rowlist,
    float* __restrict__ out, float* __restrict__ c_buf,
    short* __restrict__ ab_w, int kk)
{
    __shared__ short A_lds[2][128 * 128];      // 2 x 32KB ([row][128 shorts], swizzled)
    __shared__ short B_lds[8][2][4][512];      // 2 x 32KB wave-private frags
    const int nk = counts[kk];
    const int base = offs[kk];
    const int ntile = 2 * ((nk + 127) >> 7);
    int tile = blockIdx.x;
    if (tile >= ntile) return;                  // block-uniform
    const int cb = blockIdx.x & 1;              // gridDim even -> cb constant per block
    const int tid = threadIdx.x;
    const int w = tid >> 6, l = tid & 63;
    const int lr = l >> 4, lc = l & 15;

    // per-lane precomputes
    int physk[4];                               // A-read swizzled 16B slot per (ks&3)
    #pragma unroll
    for (int c = 0; c < 4; ++c) physk[c] = (c * 4 + lr) ^ lc;
    int ssrc[4];                                // A-issue per-lane src offset (shorts)
    #pragma unroll
    for (int i = 0; i < 4; ++i) {
        const int sp_ = lc ^ (i * 4 + lr);      // logical slot stored at this lane's dest
        ssrc[i] = (sp_ >> 2) * 32 + (sp_ & 3) * 8;
    }

    const int u = cb * 128 + w * 16 + lc;
    const float bI = bias[u], bF = bias[256 + u], bG = bias[512 + u], bO = bias[768 + u];

#define LOAD_P(row0v, P0, P1, P2, P3)                                           \
    {                                                                           \
        int r_;                                                                 \
        r_ = (row0v) + w * 16 + 0 + lr;  P0 = rowlist[base + (r_ < nk ? r_ : 0)]; \
        r_ = (row0v) + w * 16 + 4 + lr;  P1 = rowlist[base + (r_ < nk ? r_ : 0)]; \
        r_ = (row0v) + w * 16 + 8 + lr;  P2 = rowlist[base + (r_ < nk ? r_ : 0)]; \
        r_ = (row0v) + w * 16 + 12 + lr; P3 = rowlist[base + (r_ < nk ? r_ : 0)]; \
    }
#define ISSUE_A(gv, P0, P1, P2, P3)                                             \
    {                                                                           \
        dma16(ab + (size_t)(P0) * 512 + (gv) * 128 + ssrc[0], &A_lds[(gv) & 1][(w * 16 + 0) * 128]);  \
        dma16(ab + (size_t)(P1) * 512 + (gv) * 128 + ssrc[1], &A_lds[(gv) & 1][(w * 16 + 4) * 128]);  \
        dma16(ab + (size_t)(P2) * 512 + (gv) * 128 + ssrc[2], &A_lds[(gv) & 1][(w * 16 + 8) * 128]);  \
        dma16(ab + (size_t)(P3) * 512 + (gv) * 128 + ssrc[3], &A_lds[(gv) & 1][(w * 16 + 12) * 128]); \
    }
#define ISSUE_B(ksv)                                                            \
    {                                                                           \
        _Pragma("unroll") for (int f = 0; f < 4; ++f) {                         \
            const int nt = f * 16 + cb * 8 + w;                                 \
            dma16(Wb + (((size_t)nt * 16 + (ksv)) * 64 + l) * 8, &B_lds[w][(ksv) & 1][f][0]); \
        }                                                                       \
    }

    // ---- prologue: first tile's A-chunk0 + B(0) ----
    int P0, P1, P2, P3;
    {
        const int r0 = (tile >> 1) * 128;
        LOAD_P(r0, P0, P1, P2, P3);
        ISSUE_A(0, P0, P1, P2, P3);
        ISSUE_B(0);
    }

    for (;;) {
        const int row0 = (tile >> 1) * 128;

        f32x4 acc[4][8];
        #pragma unroll
        for (int gt = 0; gt < 4; ++gt)
            #pragma unroll
            for (int mb = 0; mb < 8; ++mb)
                acc[gt][mb] = (f32x4){0.f, 0.f, 0.f, 0.f};

        #pragma unroll
        for (int g = 0; g < 4; ++g) {
            #pragma unroll
            for (int ksl = 0; ksl < 4; ++ksl) {
                const int ks = g * 4 + ksl;
                ISSUE_B((ks + 1) & 15);                    // ks15 -> B(0) of next tile
                if (ksl == 0 && g < 3) ISSUE_A(g + 1, P0, P1, P2, P3);
                if (g < 3 && ksl <= 1) { asm volatile("s_waitcnt vmcnt(8)" ::: "memory"); }
                else                   { asm volatile("s_waitcnt vmcnt(4)" ::: "memory"); }
                __builtin_amdgcn_sched_barrier(0);
                if (ksl == 0) __syncthreads();             // A-chunk(g) landed block-wide

                const short8 b0 = *(const short8*)&B_lds[w][ks & 1][0][l * 8];
                const short8 b1 = *(const short8*)&B_lds[w][ks & 1][1][l * 8];
                const short8 b2 = *(const short8*)&B_lds[w][ks & 1][2][l * 8];
                const short8 b3 = *(const short8*)&B_lds[w][ks & 1][3][l * 8];
                #pragma unroll
                for (int mb = 0; mb < 8; ++mb) {
                    const short8 a = *(const short8*)&A_lds[g & 1][(mb * 16 + lc) * 128 + physk[ksl] * 8];
                    acc[0][mb] = __builtin_amdgcn_mfma_f32_16x16x32_bf16(a, b0, acc[0][mb], 0, 0, 0);
                    acc[1][mb] = __builtin_amdgcn_mfma_f32_16x16x32_bf16(a, b1, acc[1][mb], 0, 0, 0);
                    acc[2][mb] = __builtin_amdgcn_mfma_f32_16x16x32_bf16(a, b2, acc[2][mb], 0, 0, 0);
                    acc[3][mb] = __builtin_amdgcn_mfma_f32_16x16x32_bf16(a, b3, acc[3][mb], 0, 0, 0);
                }
            }
            __syncthreads();                               // all waves done with A-chunk(g)
        }

        // ---- prefetch next tile's A-chunk0 (buf0: free since g2-end) ----
        const int tnext = tile + gridDim.x;
        const bool more = (tnext < ntile);
        int Q0 = 0, Q1 = 0, Q2 = 0, Q3 = 0;
        if (more) {
            const int r0n = (tnext >> 1) * 128;
            LOAD_P(r0n, Q0, Q1, Q2, Q3);
            ISSUE_A(0, Q0, Q1, Q2, Q3);
        }

        // ---- epilogue: fused LSTM pointwise (thread owns unit u, rows lr*4+j per mb) ----
        #pragma unroll
        for (int mb = 0; mb < 8; ++mb) {
            #pragma unroll
            for (int j = 0; j < 4; ++j) {
                const int gr = row0 + mb * 16 + lr * 4 + j;
                if (gr < nk) {
                    const int pos = rowlist[base + gr];
                    float cp = 0.0f;
                    if (kk > 0)           cp = c_buf[(size_t)(pos - B_DIM) * H_DIM + u];
                    else if (!done[pos])  cp = c0[(size_t)(pos & (B_DIM - 1)) * H_DIM + u];
                    const float si = sigm(acc[0][mb][j] + bI);
                    const float sf = sigm(acc[1][mb][j] + bF);
                    const float tg = tanh_fast(acc[2][mb][j] + bG);
                    const float so = sigm(acc[3][mb][j] + bO);
                    const float cn = sf * cp + si * tg;
                    const float hn = so * tanh_fast(cn);
                    c_buf[(size_t)pos * H_DIM + u] = cn;
                    out[(size_t)pos * H_DIM + u]  = hn;
                    const int sp = pos + B_DIM;            // successor row's ab h-half
                    if (sp < T_DIM * B_DIM && !done[sp])
                        ab_w[(size_t)sp * 512 + 256 + u] = (short)f2bf(hn);
                }
            }
        }

        if (!more) break;
        P0 = Q0; P1 = Q1; P2 = Q2; P3 = Q3;
        tile = tnext;
    }
#undef LOAD_P
#undef ISSUE_A
#undef ISSUE_B
}

// ================== legacy round (non-ab fallback, proven R8 path) ==================
__global__ __launch_bounds__(512, 1) void k_round_legacy(
    const float* __restrict__ x, const float* __restrict__ h0,
    const float* __restrict__ c0, const int* __restrict__ done,
    const short* __restrict__ Wb, const float* __restrict__ bias,
    const int* __restrict__ counts, const int* __restrict__ offs,
    const int* __restrict__ rowlist,
    float* __restrict__ out, float* __restrict__ c_buf, int kk)
{
    __shared__ short A_lds[16 * 4 * 64 * 8];
    __shared__ short B_lds[8][8][64 * 8];
    __shared__ int posr[64];
    const int nk = counts[kk];
    const int base = offs[kk];
    const int tid = threadIdx.x;
    const int w = tid >> 6, l = tid & 63;
    const int lr = l >> 4, lc = l & 15;

    const int u_pw = w * 32 + lc;
    float bI[2], bF[2], bG[2], bO[2];
    #pragma unroll
    for (int uq = 0; uq < 2; ++uq) {
        bI[uq] = bias[u_pw + uq * 16];
        bF[uq] = bias[256 + u_pw + uq * 16];
        bG[uq] = bias[512 + u_pw + uq * 16];
        bO[uq] = bias[768 + u_pw + uq * 16];
    }

#define ISSUE_BL(ksv)                                                           \
    {                                                                           \
        _Pragma("unroll") for (int f = 0; f < 8; ++f) {                         \
            const int nt = (f >> 1) * 16 + w * 2 + (f & 1);                     \
            dma16(Wb + (((size_t)nt * 16 + (ksv)) * 64 + l) * 8, &B_lds[w][f][0]); \
        }                                                                       \
    }

    for (int tile = blockIdx.x; tile * 64 < nk; tile += gridDim.x) {
        const int row0 = tile * 64;
        if (tid < 64)
            posr[tid] = (row0 + tid < nk) ? rowlist[base + row0 + tid] : -1;
        __syncthreads();

        unsigned long long* A_u64 = (unsigned long long*)A_lds;
        #pragma unroll 4
        for (int it = 0; it < 16; ++it) {
            const int q = it * 512 + tid;
            const int ks = q >> 9, mb = (q >> 7) & 3, sl = (q >> 1) & 63, jq = q & 1;
            const int r = mb * 16 + (sl & 15);
            const int c = ks * 32 + ((sl >> 4) << 3) + 4 * jq;
            const int pos = posr[r];
            float4 v = {0.f, 0.f, 0.f, 0.f};
            if (pos >= 0) {
                if (c < D_DIM) {
                    v = *(const float4*)(x + (size_t)pos * D_DIM + c);
                } else {
                    const int uu = c - D_DIM;
                    if (kk > 0)          v = *(const float4*)(out + (size_t)(pos - B_DIM) * H_DIM + uu);
                    else if (!done[pos]) v = *(const float4*)(h0 + (size_t)(pos & (B_DIM - 1)) * H_DIM + uu);
                }
            }
            A_u64[q] = pack4(v);
        }
        __syncthreads();

        f32x4 acc[4][4][2];
        #pragma unroll
        for (int gt = 0; gt < 4; ++gt)
            #pragma unroll
            for (int mb = 0; mb < 4; ++mb)
                #pragma unroll
                for (int uq = 0; uq < 2; ++uq)
                    acc[gt][mb][uq] = (f32x4){0.f, 0.f, 0.f, 0.f};

        ISSUE_BL(0);
        #pragma unroll 1
        for (int ks = 0; ks < 16; ++ks) {
            asm volatile("s_waitcnt vmcnt(0)" ::: "memory");
            short8 b[8];
            #pragma unroll
            for (int f = 0; f < 8; ++f)
                b[f] = *(const short8*)&B_lds[w][f][l * 8];
            asm volatile("s_waitcnt lgkmcnt(0)" ::: "memory");
            __builtin_amdgcn_sched_barrier(0);
            if (ks + 1 < 16) ISSUE_BL(ks + 1);
            #pragma unroll
            for (int mb = 0; mb < 4; ++mb) {
                const short8 a = *(const short8*)&A_lds[((ks * 4 + mb) * 64 + l) * 8];
                #pragma unroll
                for (int f = 0; f < 8; ++f)
                    acc[f >> 1][mb][f & 1] = __builtin_amdgcn_mfma_f32_16x16x32_bf16(
                        a, b[f], acc[f >> 1][mb][f & 1], 0, 0, 0);
            }
        }

        #pragma unroll
        for (int mb = 0; mb < 4; ++mb) {
            #pragma unroll
            for (int uq = 0; uq < 2; ++uq) {
                const int uu = w * 32 + uq * 16 + lc;
                #pragma unroll
                for (int j = 0; j < 4; ++j) {
                    const int gr = row0 + mb * 16 + lr * 4 + j;
                    if (gr < nk) {
                        const int pos = posr[mb * 16 + lr * 4 + j];
                        float cp = 0.0f;
                        if (kk > 0)           cp = c_buf[(size_t)(pos - B_DIM) * H_DIM + uu];
                        else if (!done[pos])  cp = c0[(size_t)(pos & (B_DIM - 1)) * H_DIM + uu];
                        const float si = sigm(acc[0][mb][uq][j] + bI[uq]);
                        const float sf = sigm(acc[1][mb][uq][j] + bF[uq]);
                        const float tg = tanh_fast(acc[2][mb][uq][j] + bG[uq]);
                        const float so = sigm(acc[3][mb][uq][j] + bO[uq]);
                        const float cn = sf * cp + si * tg;
                        const float hn = so * tanh_fast(cn);
                        c_buf[(size_t)pos * H_DIM + uu] = cn;
                        out[(size_t)pos * H_DIM + uu]  = hn;
                    }
                }
            }
        }
        __syncthreads();
    }
#undef ISSUE_BL
}

// Per-segment sequential finisher for steps >= CHAIN_K (independent chains).
__global__ __launch_bounds__(1024) void k_finish(
    const float* __restrict__ x, const unsigned long long* __restrict__ Wq,
    const float* __restrict__ bias,
    const int* __restrict__ counts, const int* __restrict__ offs,
    const int* __restrict__ rowlist, const int* __restrict__ kmap,
    float* __restrict__ out, float* __restrict__ c_buf)
{
    __shared__ float abuf[K_DIM];
    __shared__ float dots[G_DIM];
    const int g = threadIdx.x;
    const int nch = counts[CHAIN_K];

    for (int m = blockIdx.x; m < nch; m += gridDim.x) {
        const int pos0 = rowlist[offs[CHAIN_K] + m];
        float c_u = 0.0f;
        if (g < H_DIM) {
            abuf[H_DIM + g] = out[(size_t)(pos0 - B_DIM) * H_DIM + g];
            c_u = c_buf[(size_t)(pos0 - B_DIM) * H_DIM + g];
        }
        int pos = pos0, step = CHAIN_K;
        while (true) {
            if (g < H_DIM) abuf[g] = x[(size_t)pos * D_DIM + g];
            __syncthreads();
            float dot = bias[g];
            #pragma unroll 8
            for (int kq = 0; kq < K_DIM / 4; ++kq) {
                const unsigned long long wq = Wq[(size_t)kq * G_DIM + g];
                const float4 a = *(const float4*)&abuf[kq * 4];
                const unsigned int wlo = (unsigned int)wq;
                const unsigned int whi = (unsigned int)(wq >> 32);
                const float w0 = __uint_as_float(wlo << 16);
                const float w1 = __uint_as_float(wlo & 0xFFFF0000u);
                const float w2 = __uint_as_float(whi << 16);
                const float w3 = __uint_as_float(whi & 0xFFFF0000u);
                dot = fmaf(a.x, w0, dot);
                dot = fmaf(a.y, w1, dot);
                dot = fmaf(a.z, w2, dot);
                dot = fmaf(a.w, w3, dot);
            }
            dots[g] = dot;
            __syncthreads();
            if (g < H_DIM) {
                const float si = sigm(dots[g]);
                const float sf = sigm(dots[H_DIM + g]);
                const float tg = tanh_fast(dots[2 * H_DIM + g]);
                const float so = sigm(dots[3 * H_DIM + g]);
                c_u = sf * c_u + si * tg;
                const float hn = so * tanh_fast(c_u);
                out[(size_t)pos * H_DIM + g]   = hn;
                c_buf[(size_t)pos * H_DIM + g] = c_u;
                abuf[H_DIM + g] = hn;
            }
            pos += B_DIM;
            ++step;
            __syncthreads();
            if (pos >= T_DIM * B_DIM) break;
            if (kmap[pos] != step) break;
        }
        __syncthreads();
    }
}

__global__ __launch_bounds__(256) void k_final(const float* __restrict__ c_buf, float* __restrict__ out)
{
    const size_t i = (size_t)blockIdx.x * 256 + threadIdx.x;
    const size_t featN = (size_t)T_DIM * B_DIM * H_DIM;
    const size_t last  = (size_t)(T_DIM - 1) * B_DIM * H_DIM;
    out[featN + i] = out[last + i];
    out[featN + (size_t)B_DIM * H_DIM + i] = c_buf[last + i];
}

__global__ __launch_bounds__(64) void k_zero(int* __restrict__ counts)
{
    if (threadIdx.x < NROUNDS) counts[threadIdx.x] = 0;
}

extern "C" void kernel_launch(void* const* d_in, const int* in_sizes, int n_in,
                              void* d_out, int out_size, void* d_ws, size_t ws_size,
                              hipStream_t stream)
{
    const float* x    = (const float*)d_in[0];
    const float* h0   = (const float*)d_in[1];
    const float* c0   = (const float*)d_in[2];
    const float* W_ih = (const float*)d_in[3];
    const float* W_hh = (const float*)d_in[4];
    const float* b_ih = (const float*)d_in[5];
    const float* b_hh = (const float*)d_in[6];
    const int*   done = (const int*)d_in[7];
    float* out = (float*)d_out;

    const size_t TB = (size_t)T_DIM * B_DIM;
    char* ws = (char*)d_ws;
    size_t off = 0;
    float* c_buf = (float*)(ws + off);            off += TB * H_DIM * 4;            // 128 MiB
    unsigned int* Wb = (unsigned int*)(ws + off); off += (size_t)(K_DIM / 2) * G_DIM * 4;
    unsigned long long* Wq = (unsigned long long*)(ws + off); off += (size_t)(K_DIM / 4) * G_DIM * 8;
    float* bias = (float*)(ws + off);             off += (size_t)G_DIM * 4;
    int* kmap    = (int*)(ws + off);              off += TB * 4;
    int* rowlist = (int*)(ws + off);              off += TB * 4;
    int* counts  = (int*)(ws + off);              off += 256;
    int* offs    = (int*)(ws + off);              off += 256;
    int* cursor  = (int*)(ws + off);              off += 256;
    short* ab = (short*)(ws + off);               // TB*512 bf16 = 128 MiB (optional)
    const size_t need_ab = off + TB * 512 * 2;
    const bool big = (ws_size >= need_ab);

    k_zero<<<1, 64, 0, stream>>>(counts);
    k_prep_weights<<<1024, 256, 0, stream>>>(W_ih, W_hh, b_ih, b_hh, Wb, bias);
    k_prep_wq<<<512, 256, 0, stream>>>(W_ih, W_hh, Wq);
    if (big) {
        k_prep_ab<<<(int)(TB * 64 / 256), 256, 0, stream>>>(x, (unsigned long long*)ab);
        k_prefill<<<(int)(TB * 32 / 256), 256, 0, stream>>>(h0, done, (unsigned long long*)ab);
    }
    k_kmap<<<T_DIM, 256, 0, stream>>>(done, kmap, counts);
    k_offs<<<1, 64, 0, stream>>>(counts, offs, cursor);
    k_scatter<<<(int)(TB / 256), 256, 0, stream>>>(kmap, offs, cursor, rowlist);

    int est = 70000;   // statistical upper bound on round-0 rows; ~halves each round
    for (int k = 0; k < CHAIN_K; ++k) {
        if (big) {
            int grid = 2 * (est / 128 + 1);
            if (grid > 256) grid = 256;
            grid &= ~1;                      // even: cb constant per block
            if (grid < 2) grid = 2;
            k_round<<<grid, 512, 0, stream>>>((const short*)ab, c0, done, (const short*)Wb,
                                              bias, counts, offs, rowlist, out, c_buf, ab, k);
        } else {
            int grid = est / 64 + 2;
            if (grid > 256) grid = 256;
            if (grid < 8) grid = 8;
            k_round_legacy<<<grid, 512, 0, stream>>>(x, h0, c0, done, (const short*)Wb, bias,
                                                     counts, offs, rowlist, out, c_buf, k);
        }
        est >>= 1;
    }
    k_finish<<<256, 1024, 0, stream>>>(x, Wq, bias, counts, offs, rowlist, kmap, out, c_buf);
    k_final<<<B_DIM * H_DIM / 256, 256, 0, stream>>>(c_buf, out);
}

// Round 12
// 713.561 us; speedup vs baseline: 1.6464x; 1.6464x over previous
//
#include <hip/hip_runtime.h>
#include <math.h>

#define T_DIM 512
#define B_DIM 256
#define D_DIM 256
#define H_DIM 256
#define G_DIM 1024   // 4*H
#define K_DIM 512    // D + H
#define NROUNDS 40
#define CHAIN_K 16   // rounds 0..15 batched; steps >=16 via per-segment finisher

typedef __attribute__((ext_vector_type(8))) short short8;
typedef __attribute__((ext_vector_type(4))) float f32x4;

__device__ __forceinline__ unsigned int f2bf(float f) {
    unsigned int b = __float_as_uint(f);
    return (b + 0x7FFFu + ((b >> 16) & 1u)) >> 16;   // round-to-nearest-even bf16
}
__device__ __forceinline__ unsigned long long pack4(float4 v) {
    const unsigned int lo = (f2bf(v.y) << 16) | f2bf(v.x);
    const unsigned int hi = (f2bf(v.w) << 16) | f2bf(v.z);
    return ((unsigned long long)hi << 32) | lo;
}
__device__ __forceinline__ float sigm(float x) { return 1.0f / (1.0f + __expf(-x)); }
__device__ __forceinline__ float tanh_fast(float x) { return 2.0f / (1.0f + __expf(-2.0f * x)) - 1.0f; }

// async 16B/lane global->LDS (dest = wave-uniform base + lane*16; SOURCE is per-lane)
__device__ __forceinline__ void dma16(const void* g, void* l) {
    __builtin_amdgcn_global_load_lds(
        (const __attribute__((address_space(1))) void*)g,
        (__attribute__((address_space(3))) void*)l, 16, 0, 0);
}

// Prepack W into MFMA B-fragment order, bf16.
// short idx ((nt*16+ks)*64+l)*8+j  <->  g = nt*16+(l&15), k = ks*32+((l>>4)<<3)+j
__global__ __launch_bounds__(256) void k_prep_weights(
    const float* __restrict__ W_ih, const float* __restrict__ W_hh,
    const float* __restrict__ b_ih, const float* __restrict__ b_hh,
    unsigned int* __restrict__ Wb, float* __restrict__ bias)
{
    const int idx = blockIdx.x * 256 + threadIdx.x;   // 0 .. 262143
    const int jp = idx & 3, l = (idx >> 2) & 63, ks = (idx >> 8) & 15, nt = idx >> 12;
    const int g = nt * 16 + (l & 15);
    const int k0 = ks * 32 + ((l >> 4) << 3) + 2 * jp;
    const float w0 = (k0 < D_DIM) ? W_ih[g * D_DIM + k0] : W_hh[g * H_DIM + (k0 - D_DIM)];
    const float w1 = (k0 + 1 < D_DIM) ? W_ih[g * D_DIM + k0 + 1] : W_hh[g * H_DIM + (k0 + 1 - D_DIM)];
    Wb[idx] = (f2bf(w1) << 16) | f2bf(w0);
    if (idx < G_DIM) bias[idx] = b_ih[idx] + b_hh[idx];
}

// Prepack W k-major for the finisher GEMV.
__global__ __launch_bounds__(256) void k_prep_wq(
    const float* __restrict__ W_ih, const float* __restrict__ W_hh,
    unsigned long long* __restrict__ Wq)
{
    const int idx = blockIdx.x * 256 + threadIdx.x;   // 0..131071
    const int kq = idx >> 10, g = idx & (G_DIM - 1);
    float w[4];
    #pragma unroll
    for (int j = 0; j < 4; ++j) {
        const int k = kq * 4 + j;
        w[j] = (k < D_DIM) ? W_ih[g * D_DIM + k] : W_hh[g * H_DIM + (k - D_DIM)];
    }
    Wq[idx] = pack4((float4){w[0], w[1], w[2], w[3]});
}

// ab x-half: ab[pos*512 + k] = bf16(x[pos][k]), k 0..255 (linear order).
__global__ __launch_bounds__(256) void k_prep_ab(
    const float* __restrict__ x, unsigned long long* __restrict__ ab_u64)
{
    const int idx = blockIdx.x * 256 + threadIdx.x;      // (pos, 16B chunk): TB*64
    const int pos = idx >> 6, ch = idx & 63;             // ch < 32 -> x half only
    if (ch >= 32) return;
    const float4 v0 = *(const float4*)(x + (size_t)pos * D_DIM + ch * 8);
    const float4 v1 = *(const float4*)(x + (size_t)pos * D_DIM + ch * 8 + 4);
    ab_u64[(size_t)pos * 128 + ch * 2]     = pack4(v0);
    ab_u64[(size_t)pos * 128 + ch * 2 + 1] = pack4(v1);
}

// ab h-half prefill for reset rows (done==1 -> 0) and t==0 (!done -> h0).
__global__ __launch_bounds__(256) void k_prefill(
    const float* __restrict__ h0, const int* __restrict__ done,
    unsigned long long* __restrict__ ab_u64)
{
    const int idx = blockIdx.x * 256 + threadIdx.x;      // (pos, chunk32): TB*32
    const int pos = idx >> 5, ch = idx & 31;
    const int d = done[pos];
    if (!d && pos >= B_DIM) return;                      // not a reset row
    unsigned long long v0 = 0ull, v1 = 0ull;
    if (!d) {                                            // t==0, use h0
        const float4 a = *(const float4*)(h0 + (size_t)(pos & (B_DIM - 1)) * H_DIM + ch * 8);
        const float4 b = *(const float4*)(h0 + (size_t)(pos & (B_DIM - 1)) * H_DIM + ch * 8 + 4);
        v0 = pack4(a); v1 = pack4(b);
    }
    ab_u64[(size_t)pos * 128 + 64 + ch * 2]     = v0;
    ab_u64[(size_t)pos * 128 + 64 + ch * 2 + 1] = v1;
}

// Parallel kmap + histogram (kmap = true steps since reset; bins clamp).
__global__ __launch_bounds__(256) void k_kmap(
    const int* __restrict__ done, int* __restrict__ kmap, int* __restrict__ counts)
{
    __shared__ int lcnt[NROUNDS];
    const int tid = threadIdx.x;
    if (tid < NROUNDS) lcnt[tid] = 0;
    __syncthreads();
    const int t = blockIdx.x, b = tid;
    int kv = t;
    for (int tt = t; tt >= 0; --tt) {
        if (done[tt * B_DIM + b]) { kv = t - tt; break; }
    }
    kmap[t * B_DIM + b] = kv;
    const int bin = kv < NROUNDS ? kv : NROUNDS - 1;
    atomicAdd(&lcnt[bin], 1);
    __syncthreads();
    if (tid < NROUNDS && lcnt[tid] > 0) atomicAdd(&counts[tid], lcnt[tid]);
}

__global__ __launch_bounds__(64) void k_offs(
    const int* __restrict__ counts, int* __restrict__ offs, int* __restrict__ cursor)
{
    if (threadIdx.x == 0) {
        int s = 0;
        for (int i = 0; i < NROUNDS; ++i) { offs[i] = s; s += counts[i]; }
    }
    if (threadIdx.x < NROUNDS) cursor[threadIdx.x] = 0;
}

__global__ __launch_bounds__(256) void k_scatter(
    const int* __restrict__ kmap, const int* __restrict__ offs,
    int* __restrict__ cursor, int* __restrict__ rowlist)
{
    __shared__ int lcnt[NROUNDS];
    __shared__ int gbase[NROUNDS];
    const int tid = threadIdx.x;
    if (tid < NROUNDS) lcnt[tid] = 0;
    __syncthreads();
    const int pos = blockIdx.x * 256 + tid;
    const int kv0 = kmap[pos];
    const int kv = kv0 < NROUNDS ? kv0 : NROUNDS - 1;
    const int lrank = atomicAdd(&lcnt[kv], 1);
    __syncthreads();
    if (tid < NROUNDS && lcnt[tid] > 0) gbase[tid] = atomicAdd(&cursor[tid], lcnt[tid]);
    __syncthreads();
    rowlist[offs[kv] + gbase[kv] + lrank] = pos;
}

// ================== B-resident-register round ==================
// 4 col-blocks (cb = blockIdx&3) of 256 gates (64 units). Block 512 thr (8 waves).
// Wave w: q=w&3, gth=w>>2; owns nt(uq) = (2*gth+uq)*16 + cb*4 + q  (uq 0,1)
//   -> whole-K B slice in regs: breg[uq][ks] = 32 short8 = 128 VGPR, loaded ONCE.
// A: 32-row tiles from ab, 1 dma16 per row (contiguous 1KB, XOR src-swizzle by r&15),
//    double-buffered 2x32KB. Gate-exchange scratch scr[4][64][36] f32 (36KB).
// Raw s_barrier + manual counted waits (no vmcnt drain at exchange barrier).
__global__ __launch_bounds__(512, 2) void k_round(
    const short* __restrict__ ab, const float* __restrict__ c0,
    const int* __restrict__ done,
    const short* __restrict__ Wb, const float* __restrict__ bias,
    const int* __restrict__ counts, const int* __restrict__ offs,
    const int* __restrict__ rowlist,
    float* __restrict__ out, float* __restrict__ c_buf,
    short* __restrict__ ab_w, int kk)
{
    __shared__ short A_lds[2 * 32 * 512];        // 64 KiB (2 bufs x 32 rows x 1KB)
    __shared__ float scr[4 * 64 * 36];           // 36 KiB gate exchange
    const int nk = counts[kk];
    const int base = offs[kk];
    const int ntiles = (nk + 31) >> 5;
    const int cb = blockIdx.x & 3;
    const int rstride = gridDim.x >> 2;
    int rt = blockIdx.x >> 2;
    if (rt >= ntiles) return;                    // block-uniform exit (before any barrier)

    const int tid = threadIdx.x;
    const int w = tid >> 6, l = tid & 63;
    const int lr = l >> 4, lc = l & 15;
    const int q = w & 3, gth = w >> 1 >> 1;      // gth = w>>2

    // epilogue identity: thread owns unit u = cb*64 + l across rows w*4..w*4+3
    const int u_ep = cb * 64 + l;
    const float bI = bias[u_ep], bF = bias[256 + u_ep], bG = bias[512 + u_ep], bO = bias[768 + u_ep];

#define ISSUE_A(row0v, bufv)                                                     \
    {                                                                            \
        _Pragma("unroll") for (int rr = 0; rr < 4; ++rr) {                       \
            const int r_ = w * 4 + rr;                                           \
            const int gr_ = (row0v) + r_;                                        \
            if (gr_ < nk) {                                                      \
                const int p_ = rowlist[base + gr_];                              \
                dma16(ab + (size_t)p_ * 512 + ((l ^ (r_ & 15)) << 3),            \
                      &A_lds[(bufv) * 16384 + r_ * 512]);                        \
            }                                                                    \
        }                                                                        \
    }

    // ---- prologue: A(tile0) + B-regs (once) ----
    ISSUE_A(rt * 32, 0);
    short8 breg0[16], breg1[16];
    {
        const int nt0 = (2 * gth + 0) * 16 + cb * 4 + q;
        const int nt1 = (2 * gth + 1) * 16 + cb * 4 + q;
        #pragma unroll
        for (int ks = 0; ks < 16; ++ks) {
            breg0[ks] = *(const short8*)(Wb + (((size_t)nt0 * 16 + ks) * 64 + l) * 8);
            breg1[ks] = *(const short8*)(Wb + (((size_t)nt1 * 16 + ks) * 64 + l) * 8);
        }
    }

    int buf = 0;
    for (; rt < ntiles; rt += rstride) {
        const int row0 = rt * 32;

        // head: A(buf)+B landed, all waves synced; prefetch next tile into buf^1
        asm volatile("s_waitcnt vmcnt(0) lgkmcnt(0)" ::: "memory");
        __builtin_amdgcn_sched_barrier(0);
        __builtin_amdgcn_s_barrier();
        __builtin_amdgcn_sched_barrier(0);
        const int rtn = rt + rstride;
        if (rtn < ntiles) ISSUE_A(rtn * 32, buf ^ 1);

        // compute: 64 MFMA from LDS-A x reg-B
        f32x4 acc0[2], acc1[2];
        #pragma unroll
        for (int mb = 0; mb < 2; ++mb) { acc0[mb] = (f32x4){0,0,0,0}; acc1[mb] = (f32x4){0,0,0,0}; }
        #pragma unroll
        for (int ks = 0; ks < 16; ++ks) {
            #pragma unroll
            for (int mb = 0; mb < 2; ++mb) {
                const short8 a = *(const short8*)&A_lds[buf * 16384 + (mb * 16 + lc) * 512
                                                       + (((ks * 4 + lr) ^ lc) << 3)];
                acc0[mb] = __builtin_amdgcn_mfma_f32_16x16x32_bf16(a, breg0[ks], acc0[mb], 0, 0, 0);
                acc1[mb] = __builtin_amdgcn_mfma_f32_16x16x32_bf16(a, breg1[ks], acc1[mb], 0, 0, 0);
            }
        }

        // gate exchange: scr[gt][unit][row(+pad36)]
        #pragma unroll
        for (int mb = 0; mb < 2; ++mb) {
            *(f32x4*)&scr[(((2 * gth + 0) * 64 + q * 16 + lc) * 36) + mb * 16 + lr * 4] = acc0[mb];
            *(f32x4*)&scr[(((2 * gth + 1) * 64 + q * 16 + lc) * 36) + mb * 16 + lr * 4] = acc1[mb];
        }
        asm volatile("s_waitcnt lgkmcnt(0)" ::: "memory");
        __builtin_amdgcn_sched_barrier(0);
        __builtin_amdgcn_s_barrier();
        __builtin_amdgcn_sched_barrier(0);

        // epilogue: thread = (unit l, rows w*4..w*4+3)
        const f32x4 vi = *(const f32x4*)&scr[((0 * 64 + l) * 36) + w * 4];
        const f32x4 vf = *(const f32x4*)&scr[((1 * 64 + l) * 36) + w * 4];
        const f32x4 vg = *(const f32x4*)&scr[((2 * 64 + l) * 36) + w * 4];
        const f32x4 vo = *(const f32x4*)&scr[((3 * 64 + l) * 36) + w * 4];
        #pragma unroll
        for (int j = 0; j < 4; ++j) {
            const int gr = row0 + w * 4 + j;
            if (gr < nk) {
                const int pos = rowlist[base + gr];
                float cp = 0.0f;
                if (kk > 0)           cp = c_buf[(size_t)(pos - B_DIM) * H_DIM + u_ep];
                else if (!done[pos])  cp = c0[(size_t)(pos & (B_DIM - 1)) * H_DIM + u_ep];
                const float si = sigm(vi[j] + bI);
                const float sf = sigm(vf[j] + bF);
                const float tg = tanh_fast(vg[j] + bG);
                const float so = sigm(vo[j] + bO);
                const float cn = sf * cp + si * tg;
                const float hn = so * tanh_fast(cn);
                c_buf[(size_t)pos * H_DIM + u_ep] = cn;
                out[(size_t)pos * H_DIM + u_ep]  = hn;
                if (kk + 1 < CHAIN_K) {
                    const int sp = pos + B_DIM;
                    if (sp < T_DIM * B_DIM && !done[sp])
                        ab_w[(size_t)sp * 512 + 256 + u_ep] = (short)f2bf(hn);
                }
            }
        }
        buf ^= 1;
    }
#undef ISSUE_A
}

// ================== legacy round (non-ab fallback, proven R8 path) ==================
__global__ __launch_bounds__(512, 1) void k_round_legacy(
    const float* __restrict__ x, const float* __restrict__ h0,
    const float* __restrict__ c0, const int* __restrict__ done,
    const short* __restrict__ Wb, const float* __restrict__ bias,
    const int* __restrict__ counts, const int* __restrict__ offs,
    const int* __restrict__ rowlist,
    float* __restrict__ out, float* __restrict__ c_buf, int kk)
{
    __shared__ short A_lds[16 * 4 * 64 * 8];
    __shared__ short B_lds[8][8][64 * 8];
    __shared__ int posr[64];
    const int nk = counts[kk];
    const int base = offs[kk];
    const int tid = threadIdx.x;
    const int w = tid >> 6, l = tid & 63;
    const int lr = l >> 4, lc = l & 15;

    const int u_pw = w * 32 + lc;
    float bI[2], bF[2], bG[2], bO[2];
    #pragma unroll
    for (int uq = 0; uq < 2; ++uq) {
        bI[uq] = bias[u_pw + uq * 16];
        bF[uq] = bias[256 + u_pw + uq * 16];
        bG[uq] = bias[512 + u_pw + uq * 16];
        bO[uq] = bias[768 + u_pw + uq * 16];
    }

#define ISSUE_BL(ksv)                                                           \
    {                                                                           \
        _Pragma("unroll") for (int f = 0; f < 8; ++f) {                         \
            const int nt = (f >> 1) * 16 + w * 2 + (f & 1);                     \
            dma16(Wb + (((size_t)nt * 16 + (ksv)) * 64 + l) * 8, &B_lds[w][f][0]); \
        }                                                                       \
    }

    for (int tile = blockIdx.x; tile * 64 < nk; tile += gridDim.x) {
        const int row0 = tile * 64;
        if (tid < 64)
            posr[tid] = (row0 + tid < nk) ? rowlist[base + row0 + tid] : -1;
        __syncthreads();

        unsigned long long* A_u64 = (unsigned long long*)A_lds;
        #pragma unroll 4
        for (int it = 0; it < 16; ++it) {
            const int qq = it * 512 + tid;
            const int ks = qq >> 9, mb = (qq >> 7) & 3, sl = (qq >> 1) & 63, jq = qq & 1;
            const int r = mb * 16 + (sl & 15);
            const int c = ks * 32 + ((sl >> 4) << 3) + 4 * jq;
            const int pos = posr[r];
            float4 v = {0.f, 0.f, 0.f, 0.f};
            if (pos >= 0) {
                if (c < D_DIM) {
                    v = *(const float4*)(x + (size_t)pos * D_DIM + c);
                } else {
                    const int uu = c - D_DIM;
                    if (kk > 0)          v = *(const float4*)(out + (size_t)(pos - B_DIM) * H_DIM + uu);
                    else if (!done[pos]) v = *(const float4*)(h0 + (size_t)(pos & (B_DIM - 1)) * H_DIM + uu);
                }
            }
            A_u64[qq] = pack4(v);
        }
        __syncthreads();

        f32x4 acc[4][4][2];
        #pragma unroll
        for (int gt = 0; gt < 4; ++gt)
            #pragma unroll
            for (int mb = 0; mb < 4; ++mb)
                #pragma unroll
                for (int uq = 0; uq < 2; ++uq)
                    acc[gt][mb][uq] = (f32x4){0.f, 0.f, 0.f, 0.f};

        ISSUE_BL(0);
        #pragma unroll 1
        for (int ks = 0; ks < 16; ++ks) {
            asm volatile("s_waitcnt vmcnt(0)" ::: "memory");
            short8 b[8];
            #pragma unroll
            for (int f = 0; f < 8; ++f)
                b[f] = *(const short8*)&B_lds[w][f][l * 8];
            asm volatile("s_waitcnt lgkmcnt(0)" ::: "memory");
            __builtin_amdgcn_sched_barrier(0);
            if (ks + 1 < 16) ISSUE_BL(ks + 1);
            #pragma unroll
            for (int mb = 0; mb < 4; ++mb) {
                const short8 a = *(const short8*)&A_lds[((ks * 4 + mb) * 64 + l) * 8];
                #pragma unroll
                for (int f = 0; f < 8; ++f)
                    acc[f >> 1][mb][f & 1] = __builtin_amdgcn_mfma_f32_16x16x32_bf16(
                        a, b[f], acc[f >> 1][mb][f & 1], 0, 0, 0);
            }
        }

        #pragma unroll
        for (int mb = 0; mb < 4; ++mb) {
            #pragma unroll
            for (int uq = 0; uq < 2; ++uq) {
                const int uu = w * 32 + uq * 16 + lc;
                #pragma unroll
                for (int j = 0; j < 4; ++j) {
                    const int gr = row0 + mb * 16 + lr * 4 + j;
                    if (gr < nk) {
                        const int pos = posr[mb * 16 + lr * 4 + j];
                        float cp = 0.0f;
                        if (kk > 0)           cp = c_buf[(size_t)(pos - B_DIM) * H_DIM + uu];
                        else if (!done[pos])  cp = c0[(size_t)(pos & (B_DIM - 1)) * H_DIM + uu];
                        const float si = sigm(acc[0][mb][uq][j] + bI[uq]);
                        const float sf = sigm(acc[1][mb][uq][j] + bF[uq]);
                        const float tg = tanh_fast(acc[2][mb][uq][j] + bG[uq]);
                        const float so = sigm(acc[3][mb][uq][j] + bO[uq]);
                        const float cn = sf * cp + si * tg;
                        const float hn = so * tanh_fast(cn);
                        c_buf[(size_t)pos * H_DIM + uu] = cn;
                        out[(size_t)pos * H_DIM + uu]  = hn;
                    }
                }
            }
        }
        __syncthreads();
    }
#undef ISSUE_BL
}

// Per-segment sequential finisher for steps >= CHAIN_K (independent chains).
__global__ __launch_bounds__(1024) void k_finish(
    const float* __restrict__ x, const unsigned long long* __restrict__ Wq,
    const float* __restrict__ bias,
    const int* __restrict__ counts, const int* __restrict__ offs,
    const int* __restrict__ rowlist, const int* __restrict__ kmap,
    float* __restrict__ out, float* __restrict__ c_buf)
{
    __shared__ float abuf[K_DIM];
    __shared__ float dots[G_DIM];
    const int g = threadIdx.x;
    const int nch = counts[CHAIN_K];

    for (int m = blockIdx.x; m < nch; m += gridDim.x) {
        const int pos0 = rowlist[offs[CHAIN_K] + m];
        float c_u = 0.0f;
        if (g < H_DIM) {
            abuf[H_DIM + g] = out[(size_t)(pos0 - B_DIM) * H_DIM + g];
            c_u = c_buf[(size_t)(pos0 - B_DIM) * H_DIM + g];
        }
        int pos = pos0, step = CHAIN_K;
        while (true) {
            if (g < H_DIM) abuf[g] = x[(size_t)pos * D_DIM + g];
            __syncthreads();
            float dot = bias[g];
            #pragma unroll 8
            for (int kq = 0; kq < K_DIM / 4; ++kq) {
                const unsigned long long wq = Wq[(size_t)kq * G_DIM + g];
                const float4 a = *(const float4*)&abuf[kq * 4];
                const unsigned int wlo = (unsigned int)wq;
                const unsigned int whi = (unsigned int)(wq >> 32);
                const float w0 = __uint_as_float(wlo << 16);
                const float w1 = __uint_as_float(wlo & 0xFFFF0000u);
                const float w2 = __uint_as_float(whi << 16);
                const float w3 = __uint_as_float(whi & 0xFFFF0000u);
                dot = fmaf(a.x, w0, dot);
                dot = fmaf(a.y, w1, dot);
                dot = fmaf(a.z, w2, dot);
                dot = fmaf(a.w, w3, dot);
            }
            dots[g] = dot;
            __syncthreads();
            if (g < H_DIM) {
                const float si = sigm(dots[g]);
                const float sf = sigm(dots[H_DIM + g]);
                const float tg = tanh_fast(dots[2 * H_DIM + g]);
                const float so = sigm(dots[3 * H_DIM + g]);
                c_u = sf * c_u + si * tg;
                const float hn = so * tanh_fast(c_u);
                out[(size_t)pos * H_DIM + g]   = hn;
                c_buf[(size_t)pos * H_DIM + g] = c_u;
                abuf[H_DIM + g] = hn;
            }
            pos += B_DIM;
            ++step;
            __syncthreads();
            if (pos >= T_DIM * B_DIM) break;
            if (kmap[pos] != step) break;
        }
        __syncthreads();
    }
}

__global__ __launch_bounds__(256) void k_final(const float* __restrict__ c_buf, float* __restrict__ out)
{
    const size_t i = (size_t)blockIdx.x * 256 + threadIdx.x;
    const size_t featN = (size_t)T_DIM * B_DIM * H_DIM;
    const size_t last  = (size_t)(T_DIM - 1) * B_DIM * H_DIM;
    out[featN + i] = out[last + i];
    out[featN + (size_t)B_DIM * H_DIM + i] = c_buf[last + i];
}

__global__ __launch_bounds__(64) void k_zero(int* __restrict__ counts)
{
    if (threadIdx.x < NROUNDS) counts[threadIdx.x] = 0;
}

extern "C" void kernel_launch(void* const* d_in, const int* in_sizes, int n_in,
                              void* d_out, int out_size, void* d_ws, size_t ws_size,
                              hipStream_t stream)
{
    const float* x    = (const float*)d_in[0];
    const float* h0   = (const float*)d_in[1];
    const float* c0   = (const float*)d_in[2];
    const float* W_ih = (const float*)d_in[3];
    const float* W_hh = (const float*)d_in[4];
    const float* b_ih = (const float*)d_in[5];
    const float* b_hh = (const float*)d_in[6];
    const int*   done = (const int*)d_in[7];
    float* out = (float*)d_out;

    const size_t TB = (size_t)T_DIM * B_DIM;
    char* ws = (char*)d_ws;
    size_t off = 0;
    float* c_buf = (float*)(ws + off);            off += TB * H_DIM * 4;            // 128 MiB
    unsigned int* Wb = (unsigned int*)(ws + off); off += (size_t)(K_DIM / 2) * G_DIM * 4;
    unsigned long long* Wq = (unsigned long long*)(ws + off); off += (size_t)(K_DIM / 4) * G_DIM * 8;
    float* bias = (float*)(ws + off);             off += (size_t)G_DIM * 4;
    int* kmap    = (int*)(ws + off);              off += TB * 4;
    int* rowlist = (int*)(ws + off);              off += TB * 4;
    int* counts  = (int*)(ws + off);              off += 256;
    int* offs    = (int*)(ws + off);              off += 256;
    int* cursor  = (int*)(ws + off);              off += 256;
    short* ab = (short*)(ws + off);               // TB*512 bf16 = 128 MiB (optional)
    const size_t need_ab = off + TB * 512 * 2;
    const bool big = (ws_size >= need_ab);

    k_zero<<<1, 64, 0, stream>>>(counts);
    k_prep_weights<<<1024, 256, 0, stream>>>(W_ih, W_hh, b_ih, b_hh, Wb, bias);
    k_prep_wq<<<512, 256, 0, stream>>>(W_ih, W_hh, Wq);
    if (big) {
        k_prep_ab<<<(int)(TB * 64 / 256), 256, 0, stream>>>(x, (unsigned long long*)ab);
        k_prefill<<<(int)(TB * 32 / 256), 256, 0, stream>>>(h0, done, (unsigned long long*)ab);
    }
    k_kmap<<<T_DIM, 256, 0, stream>>>(done, kmap, counts);
    k_offs<<<1, 64, 0, stream>>>(counts, offs, cursor);
    k_scatter<<<(int)(TB / 256), 256, 0, stream>>>(kmap, offs, cursor, rowlist);

    int est = 70000;   // statistical upper bound on round-0 rows; ~halves each round
    for (int k = 0; k < CHAIN_K; ++k) {
        if (big) {
            int rgs = (est + 31) / 32;
            if (rgs > 64) rgs = 64;
            if (rgs < 1) rgs = 1;
            k_round<<<4 * rgs, 512, 0, stream>>>((const short*)ab, c0, done, (const short*)Wb,
                                                 bias, counts, offs, rowlist, out, c_buf, ab, k);
        } else {
            int grid = est / 64 + 2;
            if (grid > 256) grid = 256;
            if (grid < 8) grid = 8;
            k_round_legacy<<<grid, 512, 0, stream>>>(x, h0, c0, done, (const short*)Wb, bias,
                                                     counts, offs, rowlist, out, c_buf, k);
        }
        est >>= 1;
    }
    k_finish<<<64, 1024, 0, stream>>>(x, Wq, bias, counts, offs, rowlist, kmap, out, c_buf);
    k_final<<<B_DIM * H_DIM / 256, 256, 0, stream>>>(c_buf, out);
}

// Round 13
// 551.372 us; speedup vs baseline: 2.1307x; 1.2942x over previous
//
#include <hip/hip_runtime.h>
#include <math.h>

#define T_DIM 512
#define B_DIM 256
#define D_DIM 256
#define H_DIM 256
#define G_DIM 1024   // 4*H
#define K_DIM 512    // D + H
#define NROUNDS 40
#define CHAIN_K 16   // rounds 0..15 batched; steps >=16 via per-segment finisher

typedef __attribute__((ext_vector_type(8))) short short8;
typedef __attribute__((ext_vector_type(4))) float f32x4;

__device__ __forceinline__ unsigned int f2bf(float f) {
    unsigned int b = __float_as_uint(f);
    return (b + 0x7FFFu + ((b >> 16) & 1u)) >> 16;   // round-to-nearest-even bf16
}
__device__ __forceinline__ unsigned long long pack4(float4 v) {
    const unsigned int lo = (f2bf(v.y) << 16) | f2bf(v.x);
    const unsigned int hi = (f2bf(v.w) << 16) | f2bf(v.z);
    return ((unsigned long long)hi << 32) | lo;
}
__device__ __forceinline__ float sigm(float x) { return 1.0f / (1.0f + __expf(-x)); }
__device__ __forceinline__ float tanh_fast(float x) { return 2.0f / (1.0f + __expf(-2.0f * x)) - 1.0f; }

// async 16B/lane global->LDS (dest = wave-uniform base + lane*16; SOURCE is per-lane)
__device__ __forceinline__ void dma16(const void* g, void* l) {
    __builtin_amdgcn_global_load_lds(
        (const __attribute__((address_space(1))) void*)g,
        (__attribute__((address_space(3))) void*)l, 16, 0, 0);
}

// Prepack W into MFMA B-fragment order, bf16.
// short idx ((nt*16+ks)*64+l)*8+j  <->  g = nt*16+(l&15), k = ks*32+((l>>4)<<3)+j
__global__ __launch_bounds__(256) void k_prep_weights(
    const float* __restrict__ W_ih, const float* __restrict__ W_hh,
    const float* __restrict__ b_ih, const float* __restrict__ b_hh,
    unsigned int* __restrict__ Wb, float* __restrict__ bias)
{
    const int idx = blockIdx.x * 256 + threadIdx.x;   // 0 .. 262143
    const int jp = idx & 3, l = (idx >> 2) & 63, ks = (idx >> 8) & 15, nt = idx >> 12;
    const int g = nt * 16 + (l & 15);
    const int k0 = ks * 32 + ((l >> 4) << 3) + 2 * jp;
    const float w0 = (k0 < D_DIM) ? W_ih[g * D_DIM + k0] : W_hh[g * H_DIM + (k0 - D_DIM)];
    const float w1 = (k0 + 1 < D_DIM) ? W_ih[g * D_DIM + k0 + 1] : W_hh[g * H_DIM + (k0 + 1 - D_DIM)];
    Wb[idx] = (f2bf(w1) << 16) | f2bf(w0);
    if (idx < G_DIM) bias[idx] = b_ih[idx] + b_hh[idx];
}

// Prepack W k-major for the finisher GEMV.
__global__ __launch_bounds__(256) void k_prep_wq(
    const float* __restrict__ W_ih, const float* __restrict__ W_hh,
    unsigned long long* __restrict__ Wq)
{
    const int idx = blockIdx.x * 256 + threadIdx.x;   // 0..131071
    const int kq = idx >> 10, g = idx & (G_DIM - 1);
    float w[4];
    #pragma unroll
    for (int j = 0; j < 4; ++j) {
        const int k = kq * 4 + j;
        w[j] = (k < D_DIM) ? W_ih[g * D_DIM + k] : W_hh[g * H_DIM + (k - D_DIM)];
    }
    Wq[idx] = pack4((float4){w[0], w[1], w[2], w[3]});
}

// ab x-half: ab[pos*512 + k] = bf16(x[pos][k]), k 0..255 (linear order).
__global__ __launch_bounds__(256) void k_prep_ab(
    const float* __restrict__ x, unsigned long long* __restrict__ ab_u64)
{
    const int idx = blockIdx.x * 256 + threadIdx.x;      // (pos, 16B chunk): TB*64
    const int pos = idx >> 6, ch = idx & 63;             // ch < 32 -> x half only
    if (ch >= 32) return;
    const float4 v0 = *(const float4*)(x + (size_t)pos * D_DIM + ch * 8);
    const float4 v1 = *(const float4*)(x + (size_t)pos * D_DIM + ch * 8 + 4);
    ab_u64[(size_t)pos * 128 + ch * 2]     = pack4(v0);
    ab_u64[(size_t)pos * 128 + ch * 2 + 1] = pack4(v1);
}

// ab h-half prefill for reset rows (done==1 -> 0) and t==0 (!done -> h0).
__global__ __launch_bounds__(256) void k_prefill(
    const float* __restrict__ h0, const int* __restrict__ done,
    unsigned long long* __restrict__ ab_u64)
{
    const int idx = blockIdx.x * 256 + threadIdx.x;      // (pos, chunk32): TB*32
    const int pos = idx >> 5, ch = idx & 31;
    const int d = done[pos];
    if (!d && pos >= B_DIM) return;                      // not a reset row
    unsigned long long v0 = 0ull, v1 = 0ull;
    if (!d) {                                            // t==0, use h0
        const float4 a = *(const float4*)(h0 + (size_t)(pos & (B_DIM - 1)) * H_DIM + ch * 8);
        const float4 b = *(const float4*)(h0 + (size_t)(pos & (B_DIM - 1)) * H_DIM + ch * 8 + 4);
        v0 = pack4(a); v1 = pack4(b);
    }
    ab_u64[(size_t)pos * 128 + 64 + ch * 2]     = v0;
    ab_u64[(size_t)pos * 128 + 64 + ch * 2 + 1] = v1;
}

// Parallel kmap + histogram (kmap = true steps since reset; bins clamp).
__global__ __launch_bounds__(256) void k_kmap(
    const int* __restrict__ done, int* __restrict__ kmap, int* __restrict__ counts)
{
    __shared__ int lcnt[NROUNDS];
    const int tid = threadIdx.x;
    if (tid < NROUNDS) lcnt[tid] = 0;
    __syncthreads();
    const int t = blockIdx.x, b = tid;
    int kv = t;
    for (int tt = t; tt >= 0; --tt) {
        if (done[tt * B_DIM + b]) { kv = t - tt; break; }
    }
    kmap[t * B_DIM + b] = kv;
    const int bin = kv < NROUNDS ? kv : NROUNDS - 1;
    atomicAdd(&lcnt[bin], 1);
    __syncthreads();
    if (tid < NROUNDS && lcnt[tid] > 0) atomicAdd(&counts[tid], lcnt[tid]);
}

__global__ __launch_bounds__(64) void k_offs(
    const int* __restrict__ counts, int* __restrict__ offs, int* __restrict__ cursor)
{
    if (threadIdx.x == 0) {
        int s = 0;
        for (int i = 0; i < NROUNDS; ++i) { offs[i] = s; s += counts[i]; }
    }
    if (threadIdx.x < NROUNDS) cursor[threadIdx.x] = 0;
}

__global__ __launch_bounds__(256) void k_scatter(
    const int* __restrict__ kmap, const int* __restrict__ offs,
    int* __restrict__ cursor, int* __restrict__ rowlist)
{
    __shared__ int lcnt[NROUNDS];
    __shared__ int gbase[NROUNDS];
    const int tid = threadIdx.x;
    if (tid < NROUNDS) lcnt[tid] = 0;
    __syncthreads();
    const int pos = blockIdx.x * 256 + tid;
    const int kv0 = kmap[pos];
    const int kv = kv0 < NROUNDS ? kv0 : NROUNDS - 1;
    const int lrank = atomicAdd(&lcnt[kv], 1);
    __syncthreads();
    if (tid < NROUNDS && lcnt[tid] > 0) gbase[tid] = atomicAdd(&cursor[tid], lcnt[tid]);
    __syncthreads();
    rowlist[offs[kv] + gbase[kv] + lrank] = pos;
}

// ================== B-resident-register round (v2) ==================
// 4 col-blocks of 256 gates. Block 512 thr (8 waves), tile 32 rows.
// launch_bounds(512,1): 256-VGPR cap -> breg (128 VGPR) stays resident.
// XCD mapping (grid==256): rchain = xcd*8 + slot>>2, cb = slot&3 -> the 4 cb
//   blocks of one row-chain share an XCD L2 (A fetched once from HBM).
// Hoisted loads: pos/c/done for tile N carried in regs from tile N-1's head ->
//   epilogue is load-free; gather latency hides under MFMA.
__global__ __launch_bounds__(512, 1) void k_round(
    const short* __restrict__ ab, const float* __restrict__ c0,
    const int* __restrict__ done,
    const short* __restrict__ Wb, const float* __restrict__ bias,
    const int* __restrict__ counts, const int* __restrict__ offs,
    const int* __restrict__ rowlist,
    float* __restrict__ out, float* __restrict__ c_buf,
    short* __restrict__ ab_w, int kk)
{
    __shared__ short A_lds[2 * 32 * 512];        // 32 KiB (2 bufs x 32 rows x 1KB)
    __shared__ float scr[4 * 64 * 36];           // 36 KiB gate exchange
    const int nk = counts[kk];
    const int base = offs[kk];
    const int ntiles = (nk + 31) >> 5;

    int cb, rt, rstride;
    if (gridDim.x == 256) {                      // XCD-aware: same-rchain cbs share XCD
        const int xcd = blockIdx.x & 7, slot = blockIdx.x >> 3;
        cb = slot & 3;
        rt = xcd * 8 + (slot >> 2);
        rstride = 64;
    } else {
        cb = blockIdx.x & 3;
        rt = blockIdx.x >> 2;
        rstride = gridDim.x >> 2;
    }
    if (rt >= ntiles) return;                    // block-uniform exit

    const int tid = threadIdx.x;
    const int w = tid >> 6, l = tid & 63;
    const int lr = l >> 4, lc = l & 15;
    const int q = w & 3, gth = w >> 2;

    const int u_ep = cb * 64 + l;                // epilogue unit
    const float bI = bias[u_ep], bF = bias[256 + u_ep], bG = bias[512 + u_ep], bO = bias[768 + u_ep];

#define ISSUE_A(PP, bufv)                                                        \
    {                                                                            \
        _Pragma("unroll") for (int rr = 0; rr < 4; ++rr) {                       \
            const int r_ = w * 4 + rr;                                           \
            dma16(ab + (size_t)PP[rr] * 512 + ((l ^ (r_ & 15)) << 3),            \
                  &A_lds[(bufv) * 16384 + r_ * 512]);                            \
        }                                                                        \
    }
#define LOAD_NEXT(row0v, PP, CP, DN, DS)                                         \
    {                                                                            \
        _Pragma("unroll") for (int j_ = 0; j_ < 4; ++j_) {                       \
            const int gr_ = (row0v) + w * 4 + j_;                                \
            PP[j_] = rowlist[base + (gr_ < nk ? gr_ : nk - 1)];                  \
        }                                                                        \
        _Pragma("unroll") for (int j_ = 0; j_ < 4; ++j_) {                       \
            const int p_ = PP[j_];                                               \
            if (kk > 0) {                                                        \
                CP[j_] = c_buf[(size_t)(p_ - B_DIM) * H_DIM + u_ep];             \
                DN[j_] = 0;                                                      \
            } else {                                                             \
                DN[j_] = done[p_];                                               \
                CP[j_] = c0[(size_t)(p_ & (B_DIM - 1)) * H_DIM + u_ep];          \
            }                                                                    \
            const int sp_ = p_ + B_DIM;                                          \
            DS[j_] = (sp_ < T_DIM * B_DIM) ? done[sp_] : 1;                      \
        }                                                                        \
    }

    // ---- prologue: tile0 gather state + A-DMA + B-regs ----
    int posC[4], dnC[4], dsC[4]; float cpC[4];
    LOAD_NEXT(rt * 32, posC, cpC, dnC, dsC);
    ISSUE_A(posC, 0);
    short8 breg0[16], breg1[16];
    {
        const int nt0 = (2 * gth + 0) * 16 + cb * 4 + q;
        const int nt1 = (2 * gth + 1) * 16 + cb * 4 + q;
        #pragma unroll
        for (int ks = 0; ks < 16; ++ks) {
            breg0[ks] = *(const short8*)(Wb + (((size_t)nt0 * 16 + ks) * 64 + l) * 8);
            breg1[ks] = *(const short8*)(Wb + (((size_t)nt1 * 16 + ks) * 64 + l) * 8);
        }
    }

    int buf = 0;
    for (; rt < ntiles; rt += rstride) {
        const int row0 = rt * 32;

        // head: A(cur)+carried loads landed; sync; issue next tile's gather+DMA
        asm volatile("s_waitcnt vmcnt(0) lgkmcnt(0)" ::: "memory");
        __builtin_amdgcn_sched_barrier(0);
        __builtin_amdgcn_s_barrier();
        __builtin_amdgcn_sched_barrier(0);
        const int rtn = rt + rstride;
        const bool more = (rtn < ntiles);
        int posN[4], dnN[4], dsN[4]; float cpN[4];
        if (more) {
            LOAD_NEXT(rtn * 32, posN, cpN, dnN, dsN);
            ISSUE_A(posN, buf ^ 1);
        }

        // compute: 32 a-reads x 2 MFMA each, B from resident regs
        f32x4 acc0[2], acc1[2];
        #pragma unroll
        for (int mb = 0; mb < 2; ++mb) { acc0[mb] = (f32x4){0,0,0,0}; acc1[mb] = (f32x4){0,0,0,0}; }
        #pragma unroll
        for (int ks = 0; ks < 16; ++ks) {
            #pragma unroll
            for (int mb = 0; mb < 2; ++mb) {
                const short8 a = *(const short8*)&A_lds[buf * 16384 + (mb * 16 + lc) * 512
                                                       + (((ks * 4 + lr) ^ lc) << 3)];
                acc0[mb] = __builtin_amdgcn_mfma_f32_16x16x32_bf16(a, breg0[ks], acc0[mb], 0, 0, 0);
                acc1[mb] = __builtin_amdgcn_mfma_f32_16x16x32_bf16(a, breg1[ks], acc1[mb], 0, 0, 0);
            }
        }

        // gate exchange: scr[gt][unit][row(+pad36)]
        #pragma unroll
        for (int mb = 0; mb < 2; ++mb) {
            *(f32x4*)&scr[(((2 * gth + 0) * 64 + q * 16 + lc) * 36) + mb * 16 + lr * 4] = acc0[mb];
            *(f32x4*)&scr[(((2 * gth + 1) * 64 + q * 16 + lc) * 36) + mb * 16 + lr * 4] = acc1[mb];
        }
        asm volatile("s_waitcnt lgkmcnt(0)" ::: "memory");
        __builtin_amdgcn_sched_barrier(0);
        __builtin_amdgcn_s_barrier();
        __builtin_amdgcn_sched_barrier(0);

        // epilogue: load-free (pos/c/done carried in regs)
        const f32x4 vi = *(const f32x4*)&scr[((0 * 64 + l) * 36) + w * 4];
        const f32x4 vf = *(const f32x4*)&scr[((1 * 64 + l) * 36) + w * 4];
        const f32x4 vg = *(const f32x4*)&scr[((2 * 64 + l) * 36) + w * 4];
        const f32x4 vo = *(const f32x4*)&scr[((3 * 64 + l) * 36) + w * 4];
        #pragma unroll
        for (int j = 0; j < 4; ++j) {
            const int gr = row0 + w * 4 + j;
            if (gr < nk) {
                const int pos = posC[j];
                const float cp = dnC[j] ? 0.0f : cpC[j];
                const float si = sigm(vi[j] + bI);
                const float sf = sigm(vf[j] + bF);
                const float tg = tanh_fast(vg[j] + bG);
                const float so = sigm(vo[j] + bO);
                const float cn = sf * cp + si * tg;
                const float hn = so * tanh_fast(cn);
                c_buf[(size_t)pos * H_DIM + u_ep] = cn;
                out[(size_t)pos * H_DIM + u_ep]  = hn;
                if (kk + 1 < CHAIN_K && !dsC[j]) {
                    ab_w[(size_t)(pos + B_DIM) * 512 + 256 + u_ep] = (short)f2bf(hn);
                }
            }
        }

        #pragma unroll
        for (int j = 0; j < 4; ++j) { posC[j] = posN[j]; cpC[j] = cpN[j]; dnC[j] = dnN[j]; dsC[j] = dsN[j]; }
        buf ^= 1;
    }
#undef ISSUE_A
#undef LOAD_NEXT
}

// ================== legacy round (non-ab fallback, proven R8 path) ==================
__global__ __launch_bounds__(512, 1) void k_round_legacy(
    const float* __restrict__ x, const float* __restrict__ h0,
    const float* __restrict__ c0, const int* __restrict__ done,
    const short* __restrict__ Wb, const float* __restrict__ bias,
    const int* __restrict__ counts, const int* __restrict__ offs,
    const int* __restrict__ rowlist,
    float* __restrict__ out, float* __restrict__ c_buf, int kk)
{
    __shared__ short A_lds[16 * 4 * 64 * 8];
    __shared__ short B_lds[8][8][64 * 8];
    __shared__ int posr[64];
    const int nk = counts[kk];
    const int base = offs[kk];
    const int tid = threadIdx.x;
    const int w = tid >> 6, l = tid & 63;
    const int lr = l >> 4, lc = l & 15;

    const int u_pw = w * 32 + lc;
    float bI[2], bF[2], bG[2], bO[2];
    #pragma unroll
    for (int uq = 0; uq < 2; ++uq) {
        bI[uq] = bias[u_pw + uq * 16];
        bF[uq] = bias[256 + u_pw + uq * 16];
        bG[uq] = bias[512 + u_pw + uq * 16];
        bO[uq] = bias[768 + u_pw + uq * 16];
    }

#define ISSUE_BL(ksv)                                                           \
    {                                                                           \
        _Pragma("unroll") for (int f = 0; f < 8; ++f) {                         \
            const int nt = (f >> 1) * 16 + w * 2 + (f & 1);                     \
            dma16(Wb + (((size_t)nt * 16 + (ksv)) * 64 + l) * 8, &B_lds[w][f][0]); \
        }                                                                       \
    }

    for (int tile = blockIdx.x; tile * 64 < nk; tile += gridDim.x) {
        const int row0 = tile * 64;
        if (tid < 64)
            posr[tid] = (row0 + tid < nk) ? rowlist[base + row0 + tid] : -1;
        __syncthreads();

        unsigned long long* A_u64 = (unsigned long long*)A_lds;
        #pragma unroll 4
        for (int it = 0; it < 16; ++it) {
            const int qq = it * 512 + tid;
            const int ks = qq >> 9, mb = (qq >> 7) & 3, sl = (qq >> 1) & 63, jq = qq & 1;
            const int r = mb * 16 + (sl & 15);
            const int c = ks * 32 + ((sl >> 4) << 3) + 4 * jq;
            const int pos = posr[r];
            float4 v = {0.f, 0.f, 0.f, 0.f};
            if (pos >= 0) {
                if (c < D_DIM) {
                    v = *(const float4*)(x + (size_t)pos * D_DIM + c);
                } else {
                    const int uu = c - D_DIM;
                    if (kk > 0)          v = *(const float4*)(out + (size_t)(pos - B_DIM) * H_DIM + uu);
                    else if (!done[pos]) v = *(const float4*)(h0 + (size_t)(pos & (B_DIM - 1)) * H_DIM + uu);
                }
            }
            A_u64[qq] = pack4(v);
        }
        __syncthreads();

        f32x4 acc[4][4][2];
        #pragma unroll
        for (int gt = 0; gt < 4; ++gt)
            #pragma unroll
            for (int mb = 0; mb < 4; ++mb)
                #pragma unroll
                for (int uq = 0; uq < 2; ++uq)
                    acc[gt][mb][uq] = (f32x4){0.f, 0.f, 0.f, 0.f};

        ISSUE_BL(0);
        #pragma unroll 1
        for (int ks = 0; ks < 16; ++ks) {
            asm volatile("s_waitcnt vmcnt(0)" ::: "memory");
            short8 b[8];
            #pragma unroll
            for (int f = 0; f < 8; ++f)
                b[f] = *(const short8*)&B_lds[w][f][l * 8];
            asm volatile("s_waitcnt lgkmcnt(0)" ::: "memory");
            __builtin_amdgcn_sched_barrier(0);
            if (ks + 1 < 16) ISSUE_BL(ks + 1);
            #pragma unroll
            for (int mb = 0; mb < 4; ++mb) {
                const short8 a = *(const short8*)&A_lds[((ks * 4 + mb) * 64 + l) * 8];
                #pragma unroll
                for (int f = 0; f < 8; ++f)
                    acc[f >> 1][mb][f & 1] = __builtin_amdgcn_mfma_f32_16x16x32_bf16(
                        a, b[f], acc[f >> 1][mb][f & 1], 0, 0, 0);
            }
        }

        #pragma unroll
        for (int mb = 0; mb < 4; ++mb) {
            #pragma unroll
            for (int uq = 0; uq < 2; ++uq) {
                const int uu = w * 32 + uq * 16 + lc;
                #pragma unroll
                for (int j = 0; j < 4; ++j) {
                    const int gr = row0 + mb * 16 + lr * 4 + j;
                    if (gr < nk) {
                        const int pos = posr[mb * 16 + lr * 4 + j];
                        float cp = 0.0f;
                        if (kk > 0)           cp = c_buf[(size_t)(pos - B_DIM) * H_DIM + uu];
                        else if (!done[pos])  cp = c0[(size_t)(pos & (B_DIM - 1)) * H_DIM + uu];
                        const float si = sigm(acc[0][mb][uq][j] + bI[uq]);
                        const float sf = sigm(acc[1][mb][uq][j] + bF[uq]);
                        const float tg = tanh_fast(acc[2][mb][uq][j] + bG[uq]);
                        const float so = sigm(acc[3][mb][uq][j] + bO[uq]);
                        const float cn = sf * cp + si * tg;
                        const float hn = so * tanh_fast(cn);
                        c_buf[(size_t)pos * H_DIM + uu] = cn;
                        out[(size_t)pos * H_DIM + uu]  = hn;
                    }
                }
            }
        }
        __syncthreads();
    }
#undef ISSUE_BL
}

// Per-segment sequential finisher for steps >= CHAIN_K (independent chains).
__global__ __launch_bounds__(1024) void k_finish(
    const float* __restrict__ x, const unsigned long long* __restrict__ Wq,
    const float* __restrict__ bias,
    const int* __restrict__ counts, const int* __restrict__ offs,
    const int* __restrict__ rowlist, const int* __restrict__ kmap,
    float* __restrict__ out, float* __restrict__ c_buf)
{
    __shared__ float abuf[K_DIM];
    __shared__ float dots[G_DIM];
    const int g = threadIdx.x;
    const int nch = counts[CHAIN_K];

    for (int m = blockIdx.x; m < nch; m += gridDim.x) {
        const int pos0 = rowlist[offs[CHAIN_K] + m];
        float c_u = 0.0f;
        if (g < H_DIM) {
            abuf[H_DIM + g] = out[(size_t)(pos0 - B_DIM) * H_DIM + g];
            c_u = c_buf[(size_t)(pos0 - B_DIM) * H_DIM + g];
        }
        int pos = pos0, step = CHAIN_K;
        while (true) {
            if (g < H_DIM) abuf[g] = x[(size_t)pos * D_DIM + g];
            __syncthreads();
            float dot = bias[g];
            #pragma unroll 8
            for (int kq = 0; kq < K_DIM / 4; ++kq) {
                const unsigned long long wq = Wq[(size_t)kq * G_DIM + g];
                const float4 a = *(const float4*)&abuf[kq * 4];
                const unsigned int wlo = (unsigned int)wq;
                const unsigned int whi = (unsigned int)(wq >> 32);
                const float w0 = __uint_as_float(wlo << 16);
                const float w1 = __uint_as_float(wlo & 0xFFFF0000u);
                const float w2 = __uint_as_float(whi << 16);
                const float w3 = __uint_as_float(whi & 0xFFFF0000u);
                dot = fmaf(a.x, w0, dot);
                dot = fmaf(a.y, w1, dot);
                dot = fmaf(a.z, w2, dot);
                dot = fmaf(a.w, w3, dot);
            }
            dots[g] = dot;
            __syncthreads();
            if (g < H_DIM) {
                const float si = sigm(dots[g]);
                const float sf = sigm(dots[H_DIM + g]);
                const float tg = tanh_fast(dots[2 * H_DIM + g]);
                const float so = sigm(dots[3 * H_DIM + g]);
                c_u = sf * c_u + si * tg;
                const float hn = so * tanh_fast(c_u);
                out[(size_t)pos * H_DIM + g]   = hn;
                c_buf[(size_t)pos * H_DIM + g] = c_u;
                abuf[H_DIM + g] = hn;
            }
            pos += B_DIM;
            ++step;
            __syncthreads();
            if (pos >= T_DIM * B_DIM) break;
            if (kmap[pos] != step) break;
        }
        __syncthreads();
    }
}

__global__ __launch_bounds__(256) void k_final(const float* __restrict__ c_buf, float* __restrict__ out)
{
    const size_t i = (size_t)blockIdx.x * 256 + threadIdx.x;
    const size_t featN = (size_t)T_DIM * B_DIM * H_DIM;
    const size_t last  = (size_t)(T_DIM - 1) * B_DIM * H_DIM;
    out[featN + i] = out[last + i];
    out[featN + (size_t)B_DIM * H_DIM + i] = c_buf[last + i];
}

__global__ __launch_bounds__(64) void k_zero(int* __restrict__ counts)
{
    if (threadIdx.x < NROUNDS) counts[threadIdx.x] = 0;
}

extern "C" void kernel_launch(void* const* d_in, const int* in_sizes, int n_in,
                              void* d_out, int out_size, void* d_ws, size_t ws_size,
                              hipStream_t stream)
{
    const float* x    = (const float*)d_in[0];
    const float* h0   = (const float*)d_in[1];
    const float* c0   = (const float*)d_in[2];
    const float* W_ih = (const float*)d_in[3];
    const float* W_hh = (const float*)d_in[4];
    const float* b_ih = (const float*)d_in[5];
    const float* b_hh = (const float*)d_in[6];
    const int*   done = (const int*)d_in[7];
    float* out = (float*)d_out;

    const size_t TB = (size_t)T_DIM * B_DIM;
    char* ws = (char*)d_ws;
    size_t off = 0;
    float* c_buf = (float*)(ws + off);            off += TB * H_DIM * 4;            // 128 MiB
    unsigned int* Wb = (unsigned int*)(ws + off); off += (size_t)(K_DIM / 2) * G_DIM * 4;
    unsigned long long* Wq = (unsigned long long*)(ws + off); off += (size_t)(K_DIM / 4) * G_DIM * 8;
    float* bias = (float*)(ws + off);             off += (size_t)G_DIM * 4;
    int* kmap    = (int*)(ws + off);              off += TB * 4;
    int* rowlist = (int*)(ws + off);              off += TB * 4;
    int* counts  = (int*)(ws + off);              off += 256;
    int* offs    = (int*)(ws + off);              off += 256;
    int* cursor  = (int*)(ws + off);              off += 256;
    short* ab = (short*)(ws + off);               // TB*512 bf16 = 128 MiB (optional)
    const size_t need_ab = off + TB * 512 * 2;
    const bool big = (ws_size >= need_ab);

    k_zero<<<1, 64, 0, stream>>>(counts);
    k_prep_weights<<<1024, 256, 0, stream>>>(W_ih, W_hh, b_ih, b_hh, Wb, bias);
    k_prep_wq<<<512, 256, 0, stream>>>(W_ih, W_hh, Wq);
    if (big) {
        k_prep_ab<<<(int)(TB * 64 / 256), 256, 0, stream>>>(x, (unsigned long long*)ab);
        k_prefill<<<(int)(TB * 32 / 256), 256, 0, stream>>>(h0, done, (unsigned long long*)ab);
    }
    k_kmap<<<T_DIM, 256, 0, stream>>>(done, kmap, counts);
    k_offs<<<1, 64, 0, stream>>>(counts, offs, cursor);
    k_scatter<<<(int)(TB / 256), 256, 0, stream>>>(kmap, offs, cursor, rowlist);

    int est = 70000;   // statistical upper bound on round-0 rows; ~halves each round
    for (int k = 0; k < CHAIN_K; ++k) {
        if (big) {
            int rgs = (est + 31) / 32;
            if (rgs > 64) rgs = 64;
            if (rgs < 1) rgs = 1;
            k_round<<<4 * rgs, 512, 0, stream>>>((const short*)ab, c0, done, (const short*)Wb,
                                                 bias, counts, offs, rowlist, out, c_buf, ab, k);
        } else {
            int grid = est / 64 + 2;
            if (grid > 256) grid = 256;
            if (grid < 8) grid = 8;
            k_round_legacy<<<grid, 512, 0, stream>>>(x, h0, c0, done, (const short*)Wb, bias,
                                                     counts, offs, rowlist, out, c_buf, k);
        }
        est >>= 1;
    }
    k_finish<<<64, 1024, 0, stream>>>(x, Wq, bias, counts, offs, rowlist, kmap, out, c_buf);
    k_final<<<B_DIM * H_DIM / 256, 256, 0, stream>>>(c_buf, out);
}